// Round 1
// baseline (1475.645 us; speedup 1.0000x reference)
//
#include <hip/hip_runtime.h>
#include <hip/hip_bf16.h>

// Problem constants (from reference): B=128, T=512, V=50000, E=100, U=128, K=32
#define B_  128
#define T_  512
#define E_  100
#define U_  128
#define K_  32
#define G4  512   // 4*U

// ---------------------------------------------------------------------------
// Kernel A: xk[row][j] = emb[tokens[row]] @ Wk + b   for both directions.
// row = b*T + t (65536 rows), j in [0,512). Output bf16.
// Tile 16 rows per block; 256 threads, each owns 4 output columns.
// ---------------------------------------------------------------------------
__global__ __launch_bounds__(256) void xk_kernel(
    const int* __restrict__ tokens, const float* __restrict__ emb,
    const float* __restrict__ Wk_f, const float* __restrict__ b_f,
    const float* __restrict__ Wk_b, const float* __restrict__ b_b,
    __hip_bfloat16* __restrict__ xk_f, __hip_bfloat16* __restrict__ xk_b)
{
    const int TILE = 16;
    __shared__ float x_lds[TILE][E_];   // 6.4 KB
    const int row0 = blockIdx.x * TILE;
    const int tid  = threadIdx.x;

    for (int idx = tid; idx < TILE * E_; idx += 256) {
        int r = idx / E_, e = idx - r * E_;
        int tok = tokens[row0 + r];
        x_lds[r][e] = emb[(long long)tok * E_ + e];
    }
    __syncthreads();

    float acc[TILE][4];
    #pragma unroll
    for (int r = 0; r < TILE; ++r)
        acc[r][0] = acc[r][1] = acc[r][2] = acc[r][3] = 0.f;

    const float* wf0 = Wk_f + tid;
    const float* wf1 = Wk_f + tid + 256;
    const float* wb0 = Wk_b + tid;
    const float* wb1 = Wk_b + tid + 256;

    for (int e = 0; e < E_; ++e) {
        float w0 = wf0[e * G4];
        float w1 = wf1[e * G4];
        float w2 = wb0[e * G4];
        float w3 = wb1[e * G4];
        #pragma unroll
        for (int r = 0; r < TILE; ++r) {
            float xv = x_lds[r][e];
            acc[r][0] = fmaf(xv, w0, acc[r][0]);
            acc[r][1] = fmaf(xv, w1, acc[r][1]);
            acc[r][2] = fmaf(xv, w2, acc[r][2]);
            acc[r][3] = fmaf(xv, w3, acc[r][3]);
        }
    }

    float bf0 = b_f[tid], bf1 = b_f[tid + 256];
    float bb0 = b_b[tid], bb1 = b_b[tid + 256];
    #pragma unroll
    for (int r = 0; r < TILE; ++r) {
        long long row = row0 + r;
        xk_f[row * G4 + tid]       = __float2bfloat16(acc[r][0] + bf0);
        xk_f[row * G4 + tid + 256] = __float2bfloat16(acc[r][1] + bf1);
        xk_b[row * G4 + tid]       = __float2bfloat16(acc[r][2] + bb0);
        xk_b[row * G4 + tid + 256] = __float2bfloat16(acc[r][3] + bb1);
    }
}

// ---------------------------------------------------------------------------
// Kernel B: persistent-register LSTM. 256 blocks: block = (dir, batch).
// 512 threads; thread j owns gate column j with Wr[:,j] (128 f32) in VGPRs.
// h broadcast via LDS each step; gate nonlinearity + state on threads 0..127.
// h output stored bf16 at h_buf[(b*T + t)*256 + dir*128 + u].
// ---------------------------------------------------------------------------
__device__ __forceinline__ float sigmoid_f(float x) {
    return 1.f / (1.f + __expf(-x));
}
__device__ __forceinline__ float tanh_f(float x) {
    // 1 - 2/(e^{2x}+1): monotone, saturates correctly at +-1 (no inf/inf NaN)
    float e = __expf(2.f * x);
    return 1.f - 2.f / (e + 1.f);
}

__global__ __launch_bounds__(512, 2) void lstm_kernel(
    const __hip_bfloat16* __restrict__ xk_f,
    const __hip_bfloat16* __restrict__ xk_b,
    const float* __restrict__ Wr_f, const float* __restrict__ Wr_b,
    __hip_bfloat16* __restrict__ h_buf)
{
    const int bid = blockIdx.x;      // 0..255
    const int dir = bid >> 7;        // 0 = fwd, 1 = bwd
    const int b   = bid & 127;
    const int j   = threadIdx.x;     // gate column, 0..511

    const float* Wr = dir ? Wr_b : Wr_f;
    const __hip_bfloat16* xk = dir ? xk_b : xk_f;

    // Persistent recurrent weights: column j, all 128 u.
    float wr[U_];
    #pragma unroll
    for (int u = 0; u < U_; ++u) wr[u] = Wr[u * G4 + j];

    __shared__ __align__(16) float h_lds[U_];
    __shared__ float z_lds[G4];
    if (j < U_) h_lds[j] = 0.f;
    float c = 0.f;
    __syncthreads();

    for (int s = 0; s < T_; ++s) {
        const int t = dir ? (T_ - 1 - s) : s;

        float acc = __bfloat162float(xk[((long long)b * T_ + t) * G4 + j]);
        const float4* h4 = (const float4*)h_lds;
        #pragma unroll
        for (int u4 = 0; u4 < U_ / 4; ++u4) {
            float4 hv = h4[u4];
            acc = fmaf(hv.x, wr[4 * u4 + 0], acc);
            acc = fmaf(hv.y, wr[4 * u4 + 1], acc);
            acc = fmaf(hv.z, wr[4 * u4 + 2], acc);
            acc = fmaf(hv.w, wr[4 * u4 + 3], acc);
        }
        z_lds[j] = acc;
        __syncthreads();

        if (j < U_) {
            float zi = z_lds[j];
            float zf = z_lds[j + U_];
            float zg = z_lds[j + 2 * U_];
            float zo = z_lds[j + 3 * U_];
            c = sigmoid_f(zf) * c + sigmoid_f(zi) * tanh_f(zg);
            float h = sigmoid_f(zo) * tanh_f(c);
            h_lds[j] = h;
            h_buf[((long long)b * T_ + t) * 256 + dir * U_ + j] = __float2bfloat16(h);
        }
        __syncthreads();
    }
}

// ---------------------------------------------------------------------------
// Kernel C: em projection + CRF forward logZ. 128 blocks (one per batch),
// 256 threads. crf_kernel (256x32) + trans (32x32) staged in LDS.
// Per step: em[k] = sum_u h[u]*ck[u][k] (8 partials x 32 k), then
// alpha'[k] = LSE_k0(alpha[k0]+trans[k0][k]) + em[k] on wave 0 (stabilized).
// ---------------------------------------------------------------------------
__global__ __launch_bounds__(256) void crf_kernel_fn(
    const __hip_bfloat16* __restrict__ h_buf,
    const float* __restrict__ ck,     // (256, 32)
    const float* __restrict__ cb,     // (32,)
    const float* __restrict__ trans,  // (32, 32)
    float* __restrict__ out)
{
    const int b   = blockIdx.x;
    const int tid = threadIdx.x;
    const int k       = tid & 31;
    const int part_id = tid >> 5;     // 0..7

    __shared__ float ck_lds[256 * K_];   // 32 KB
    __shared__ float tr_lds[K_ * K_];    // 4 KB
    __shared__ float h_l[256];
    __shared__ float part[8][K_];
    __shared__ float alpha[K_];

    for (int i = tid; i < 256 * K_; i += 256) ck_lds[i] = ck[i];
    for (int i = tid; i < K_ * K_; i += 256) tr_lds[i] = trans[i];
    __syncthreads();

    for (int t = 0; t < T_; ++t) {
        h_l[tid] = __bfloat162float(h_buf[((long long)b * T_ + t) * 256 + tid]);
        __syncthreads();

        float p = 0.f;
        #pragma unroll
        for (int uu = 0; uu < 32; ++uu) {
            int u = part_id * 32 + uu;
            p = fmaf(h_l[u], ck_lds[u * K_ + k], p);
        }
        part[part_id][k] = p;
        __syncthreads();

        if (tid < K_) {   // single wave: lockstep makes alpha read->write safe
            float em = cb[k];
            #pragma unroll
            for (int pp = 0; pp < 8; ++pp) em += part[pp][k];

            float na;
            if (t == 0) {
                na = em;
            } else {
                float m = -1e30f;
                #pragma unroll
                for (int k0 = 0; k0 < K_; ++k0) {
                    float v = alpha[k0] + tr_lds[k0 * K_ + k];
                    m = fmaxf(m, v);
                }
                float ssum = 0.f;
                #pragma unroll
                for (int k0 = 0; k0 < K_; ++k0) {
                    float v = alpha[k0] + tr_lds[k0 * K_ + k];
                    ssum += __expf(v - m);
                }
                na = m + __logf(ssum) + em;
            }
            alpha[k] = na;
        }
        __syncthreads();
    }

    if (tid == 0) {
        float m = -1e30f;
        for (int k0 = 0; k0 < K_; ++k0) m = fmaxf(m, alpha[k0]);
        float ssum = 0.f;
        for (int k0 = 0; k0 < K_; ++k0) ssum += __expf(alpha[k0] - m);
        out[b] = m + __logf(ssum);
    }
}

// ---------------------------------------------------------------------------
extern "C" void kernel_launch(void* const* d_in, const int* in_sizes, int n_in,
                              void* d_out, int out_size, void* d_ws, size_t ws_size,
                              hipStream_t stream)
{
    const int*   tokens = (const int*)  d_in[0];
    const float* emb    = (const float*)d_in[1];
    const float* Wk_f   = (const float*)d_in[2];
    const float* Wr_f   = (const float*)d_in[3];
    const float* b_f    = (const float*)d_in[4];
    const float* Wk_b   = (const float*)d_in[5];
    const float* Wr_b   = (const float*)d_in[6];
    const float* b_b    = (const float*)d_in[7];
    const float* ck     = (const float*)d_in[8];
    const float* cb     = (const float*)d_in[9];
    const float* trans  = (const float*)d_in[10];
    float* out = (float*)d_out;

    // Workspace carve (bf16): xk_f 64M-elem, xk_b 64M-elem, h_buf 16M-elem
    // = 67.1 MB + 67.1 MB + 33.6 MB = 167.8 MB total.
    const long long ROWS = (long long)B_ * T_;     // 65536
    __hip_bfloat16* xk_f  = (__hip_bfloat16*)d_ws;
    __hip_bfloat16* xk_b  = xk_f + ROWS * G4;
    __hip_bfloat16* h_buf = xk_b + ROWS * G4;

    hipLaunchKernelGGL(xk_kernel, dim3((int)(ROWS / 16)), dim3(256), 0, stream,
                       tokens, emb, Wk_f, b_f, Wk_b, b_b, xk_f, xk_b);
    hipLaunchKernelGGL(lstm_kernel, dim3(256), dim3(512), 0, stream,
                       xk_f, xk_b, Wr_f, Wr_b, h_buf);
    hipLaunchKernelGGL(crf_kernel_fn, dim3(B_), dim3(256), 0, stream,
                       h_buf, ck, cb, trans, out);
}

// Round 2
// 906.249 us; speedup vs baseline: 1.6283x; 1.6283x over previous
//
#include <hip/hip_runtime.h>
#include <hip/hip_bf16.h>

// Problem constants: B=128, T=512, V=50000, E=100, U=128, K=32
#define B_  128
#define T_  512
#define E_  100
#define U_  128
#define K_  32
#define G4  512   // 4*U

// ---------------------------------------------------------------------------
// Kernel A: xk[row][j] = emb[tokens[row]] @ Wk + b   for both directions.
// ---------------------------------------------------------------------------
__global__ __launch_bounds__(256) void xk_kernel(
    const int* __restrict__ tokens, const float* __restrict__ emb,
    const float* __restrict__ Wk_f, const float* __restrict__ b_f,
    const float* __restrict__ Wk_b, const float* __restrict__ b_b,
    __hip_bfloat16* __restrict__ xk_f, __hip_bfloat16* __restrict__ xk_b)
{
    const int TILE = 16;
    __shared__ float x_lds[TILE][E_];
    const int row0 = blockIdx.x * TILE;
    const int tid  = threadIdx.x;

    for (int idx = tid; idx < TILE * E_; idx += 256) {
        int r = idx / E_, e = idx - r * E_;
        int tok = tokens[row0 + r];
        x_lds[r][e] = emb[(long long)tok * E_ + e];
    }
    __syncthreads();

    float acc[TILE][4];
    #pragma unroll
    for (int r = 0; r < TILE; ++r)
        acc[r][0] = acc[r][1] = acc[r][2] = acc[r][3] = 0.f;

    const float* wf0 = Wk_f + tid;
    const float* wf1 = Wk_f + tid + 256;
    const float* wb0 = Wk_b + tid;
    const float* wb1 = Wk_b + tid + 256;

    for (int e = 0; e < E_; ++e) {
        float w0 = wf0[e * G4];
        float w1 = wf1[e * G4];
        float w2 = wb0[e * G4];
        float w3 = wb1[e * G4];
        #pragma unroll
        for (int r = 0; r < TILE; ++r) {
            float xv = x_lds[r][e];
            acc[r][0] = fmaf(xv, w0, acc[r][0]);
            acc[r][1] = fmaf(xv, w1, acc[r][1]);
            acc[r][2] = fmaf(xv, w2, acc[r][2]);
            acc[r][3] = fmaf(xv, w3, acc[r][3]);
        }
    }

    float bf0 = b_f[tid], bf1 = b_f[tid + 256];
    float bb0 = b_b[tid], bb1 = b_b[tid + 256];
    #pragma unroll
    for (int r = 0; r < TILE; ++r) {
        long long row = row0 + r;
        xk_f[row * G4 + tid]       = __float2bfloat16(acc[r][0] + bf0);
        xk_f[row * G4 + tid + 256] = __float2bfloat16(acc[r][1] + bf1);
        xk_b[row * G4 + tid]       = __float2bfloat16(acc[r][2] + bb0);
        xk_b[row * G4 + tid + 256] = __float2bfloat16(acc[r][3] + bb1);
    }
}

// ---------------------------------------------------------------------------
// Kernel B: LSTM. 256 blocks = (dir, batch), 512 threads = 4 u-parts x 128 q.
// Thread (part,q) owns 4 gate columns {g*128+q} restricted to u in
// [part*32, part*32+32), with those 128 Wr values in VGPRs.
// h broadcast: 1 ds_read_b32 per wave + v_readlane -> SGPR (no LDS storm).
// xk prefetched one step ahead; partial z reduced via LDS.
// ---------------------------------------------------------------------------
__device__ __forceinline__ float sigmoid_f(float x) {
    return 1.f / (1.f + __expf(-x));
}
__device__ __forceinline__ float tanh_f(float x) {
    float e = __expf(2.f * x);
    return 1.f - 2.f / (e + 1.f);
}

__global__ __launch_bounds__(512, 2) void lstm_kernel(
    const __hip_bfloat16* __restrict__ xk_f,
    const __hip_bfloat16* __restrict__ xk_b,
    const float* __restrict__ Wr_f, const float* __restrict__ Wr_b,
    __hip_bfloat16* __restrict__ h_buf)
{
    const int bid  = blockIdx.x;
    const int dir  = bid >> 7;
    const int b    = bid & 127;
    const int tid  = threadIdx.x;
    const int part = tid >> 7;       // 0..3 : u-range [part*32, part*32+32)
    const int q    = tid & 127;      // unit / column-group index

    const float* Wr = dir ? Wr_b : Wr_f;
    const __hip_bfloat16* xk = dir ? xk_b : xk_f;

    // w[g][i] = Wr[(part*32+i)][g*128+q]
    float w[4][32];
    #pragma unroll
    for (int g = 0; g < 4; ++g)
        for (int i = 0; i < 32; ++i)
            w[g][i] = Wr[(part * 32 + i) * G4 + g * 128 + q];

    __shared__ float h_lds[U_];
    __shared__ float part_lds[4][4][U_];   // [part][gate][q]
    if (tid < U_) h_lds[tid] = 0.f;
    float c = 0.f;
    __syncthreads();

    const long long rowbase = (long long)b * T_;
    int t0 = dir ? (T_ - 1) : 0;
    float xk_cur = __bfloat162float(xk[(rowbase + t0) * G4 + part * 128 + q]);

    for (int s = 0; s < T_; ++s) {
        const int t  = dir ? (T_ - 1 - s) : s;
        const int tn = dir ? (t - 1) : (t + 1);

        // prefetch next step's xk (recursion-independent)
        float xk_nxt = 0.f;
        if (s + 1 < T_)
            xk_nxt = __bfloat162float(xk[(rowbase + tn) * G4 + part * 128 + q]);

        // h values for this wave's u-range, via one lane-distributed read
        float hv = h_lds[part * 32 + (tid & 31)];

        float acc0 = 0.f, acc1 = 0.f, acc2 = 0.f, acc3 = 0.f;
        #pragma unroll
        for (int i = 0; i < 32; ++i) {
            float hs = __int_as_float(__builtin_amdgcn_readlane(__float_as_int(hv), i));
            acc0 = fmaf(hs, w[0][i], acc0);
            acc1 = fmaf(hs, w[1][i], acc1);
            acc2 = fmaf(hs, w[2][i], acc2);
            acc3 = fmaf(hs, w[3][i], acc3);
        }
        // fold xk into this thread's matching-gate partial (gate == part)
        if (part == 0) acc0 += xk_cur;
        else if (part == 1) acc1 += xk_cur;
        else if (part == 2) acc2 += xk_cur;
        else acc3 += xk_cur;

        part_lds[part][0][q] = acc0;
        part_lds[part][1][q] = acc1;
        part_lds[part][2][q] = acc2;
        part_lds[part][3][q] = acc3;
        __syncthreads();

        if (tid < U_) {
            float zi = 0.f, zf = 0.f, zg = 0.f, zo = 0.f;
            #pragma unroll
            for (int p = 0; p < 4; ++p) {
                zi += part_lds[p][0][tid];
                zf += part_lds[p][1][tid];
                zg += part_lds[p][2][tid];
                zo += part_lds[p][3][tid];
            }
            c = sigmoid_f(zf) * c + sigmoid_f(zi) * tanh_f(zg);
            float h = sigmoid_f(zo) * tanh_f(c);
            h_lds[tid] = h;
            h_buf[(rowbase + t) * 256 + dir * U_ + tid] = __float2bfloat16(h);
        }
        __syncthreads();

        xk_cur = xk_nxt;
    }
}

// ---------------------------------------------------------------------------
// Kernel C: em = h_buf(65536x256 bf16) @ ck(256x32) + cb  -> f32 (65536x32).
// 1024 blocks x 256 threads; thread = (part 0..7, k); ck slice in registers.
// ---------------------------------------------------------------------------
__global__ __launch_bounds__(256) void em_kernel(
    const __hip_bfloat16* __restrict__ h_buf,
    const float* __restrict__ ck, const float* __restrict__ cb,
    float* __restrict__ em)
{
    const int tid  = threadIdx.x;
    const int part = tid >> 5;    // 0..7 -> u in [part*32, part*32+32)
    const int k    = tid & 31;

    float ckr[32];
    #pragma unroll
    for (int i = 0; i < 32; ++i)
        ckr[i] = ck[(part * 32 + i) * K_ + k];
    const float cbk = cb[k];

    __shared__ float h_l[8][256];
    __shared__ float part_l[8][8][K_];   // [row][part][k]

    const int r0 = blockIdx.x * 64;

    for (int round = 0; round < 8; ++round) {
        const int rbase = r0 + round * 8;
        #pragma unroll
        for (int j = 0; j < 8; ++j)
            h_l[j][tid] = __bfloat162float(h_buf[(long long)(rbase + j) * 256 + tid]);
        __syncthreads();

        #pragma unroll
        for (int j = 0; j < 8; ++j) {
            float p = 0.f;
            #pragma unroll
            for (int i = 0; i < 32; ++i)
                p = fmaf(h_l[j][part * 32 + i], ckr[i], p);
            part_l[j][part][k] = p;
        }
        __syncthreads();

        // reduce: thread = (row j2 = tid>>5, k)
        {
            int j2 = tid >> 5;
            float e = cbk;
            #pragma unroll
            for (int p = 0; p < 8; ++p) e += part_l[j2][p][k];
            em[(long long)(rbase + j2) * K_ + k] = e;
        }
        __syncthreads();
    }
}

// ---------------------------------------------------------------------------
// Kernel D: CRF logZ. 128 blocks x 1 wave. alpha in registers (lane k,
// replicated across halves). exp(trans) in registers. One exp per lane per
// step; em prefetched 8 deep. LSE shift M = alpha[0] (exact, overflow-safe).
// ---------------------------------------------------------------------------
#define PF_ 8
__global__ __launch_bounds__(64) void crf_kernel(
    const float* __restrict__ em,
    const float* __restrict__ trans,
    float* __restrict__ out)
{
    const int b    = blockIdx.x;
    const int lane = threadIdx.x;
    const int k    = lane & 31;
    const int half = lane >> 5;

    // etr[i] = exp(trans[k0][k]) for k0 = half*16 + i
    float etr[16];
    #pragma unroll
    for (int i = 0; i < 16; ++i)
        etr[i] = __expf(trans[(half * 16 + i) * K_ + k]);

    const float* em_b = em + (long long)b * T_ * K_;

    float ep[PF_];
    #pragma unroll
    for (int d = 0; d < PF_; ++d)
        ep[d] = em_b[d * K_ + k];

    float alpha = 0.f;
    for (int tb = 0; tb < T_; tb += PF_) {
        float en[PF_];
        if (tb + PF_ < T_) {
            #pragma unroll
            for (int d = 0; d < PF_; ++d)
                en[d] = em_b[(tb + PF_ + d) * K_ + k];
        } else {
            #pragma unroll
            for (int d = 0; d < PF_; ++d) en[d] = 0.f;
        }

        #pragma unroll
        for (int d = 0; d < PF_; ++d) {
            const int t = tb + d;
            if (t == 0) {
                alpha = ep[d];
            } else {
                float M = __shfl(alpha, 0, 64);        // any shift is exact
                float p = __expf(alpha - M);           // spread small: safe
                float acc = 0.f;
                #pragma unroll
                for (int i = 0; i < 16; ++i) {
                    float pv = __shfl(p, half * 16 + i, 64);
                    acc = fmaf(pv, etr[i], acc);
                }
                acc += __shfl_xor(acc, 32, 64);        // combine halves
                alpha = M + __logf(acc) + ep[d];
            }
        }
        #pragma unroll
        for (int d = 0; d < PF_; ++d) ep[d] = en[d];
    }

    // final logsumexp over k (exact max this time)
    float m = alpha;
    #pragma unroll
    for (int d = 1; d < 32; d <<= 1)
        m = fmaxf(m, __shfl_xor(m, d, 64));
    float s = __expf(alpha - m);
    #pragma unroll
    for (int d = 1; d < 32; d <<= 1)
        s += __shfl_xor(s, d, 64);
    if (lane == 0) out[b] = m + __logf(s);
}

// ---------------------------------------------------------------------------
extern "C" void kernel_launch(void* const* d_in, const int* in_sizes, int n_in,
                              void* d_out, int out_size, void* d_ws, size_t ws_size,
                              hipStream_t stream)
{
    const int*   tokens = (const int*)  d_in[0];
    const float* emb    = (const float*)d_in[1];
    const float* Wk_f   = (const float*)d_in[2];
    const float* Wr_f   = (const float*)d_in[3];
    const float* b_f    = (const float*)d_in[4];
    const float* Wk_b   = (const float*)d_in[5];
    const float* Wr_b   = (const float*)d_in[6];
    const float* b_b    = (const float*)d_in[7];
    const float* ck     = (const float*)d_in[8];
    const float* cb     = (const float*)d_in[9];
    const float* trans  = (const float*)d_in[10];
    float* out = (float*)d_out;

    // Workspace: xk_f (67.1MB) | xk_b (67.1MB) | h_buf (33.6MB).
    // em (8.4MB f32) aliases xk_f, which is dead once lstm_kernel completes.
    const long long ROWS = (long long)B_ * T_;     // 65536
    __hip_bfloat16* xk_f  = (__hip_bfloat16*)d_ws;
    __hip_bfloat16* xk_b  = xk_f + ROWS * G4;
    __hip_bfloat16* h_buf = xk_b + ROWS * G4;
    float* em = (float*)d_ws;                      // alias, safe by ordering

    hipLaunchKernelGGL(xk_kernel, dim3((int)(ROWS / 16)), dim3(256), 0, stream,
                       tokens, emb, Wk_f, b_f, Wk_b, b_b, xk_f, xk_b);
    hipLaunchKernelGGL(lstm_kernel, dim3(256), dim3(512), 0, stream,
                       xk_f, xk_b, Wr_f, Wr_b, h_buf);
    hipLaunchKernelGGL(em_kernel, dim3((int)(ROWS / 64)), dim3(256), 0, stream,
                       h_buf, ck, cb, em);
    hipLaunchKernelGGL(crf_kernel, dim3(B_), dim3(64), 0, stream,
                       em, trans, out);
}

// Round 4
// 851.662 us; speedup vs baseline: 1.7327x; 1.0641x over previous
//
#include <hip/hip_runtime.h>
#include <hip/hip_bf16.h>

// Problem constants: B=128, T=512, V=50000, E=100, U=128, K=32
#define B_  128
#define T_  512
#define E_  100
#define U_  128
#define K_  32
#define G4  512   // 4*U

typedef _Float16 h2_t __attribute__((ext_vector_type(2)));
typedef __fp16   h2raw_t __attribute__((ext_vector_type(2)));

__device__ __forceinline__ h2_t pk2(float a, float b) {
    h2raw_t r = __builtin_amdgcn_cvt_pkrtz(a, b);
    union { h2raw_t r; h2_t h; } u; u.r = r; return u.h;
}
__device__ __forceinline__ int h2_as_int(h2_t v) { union { h2_t h; int i; } u; u.h = v; return u.i; }
__device__ __forceinline__ h2_t int_as_h2(int v) { union { h2_t h; int i; } u; u.i = v; return u.h; }

#if __has_builtin(__builtin_amdgcn_fdot2)
__device__ __forceinline__ float fdot2_f(h2_t a, h2_t b, float c) {
    return __builtin_amdgcn_fdot2(a, b, c, false);
}
#else
__device__ __forceinline__ float fdot2_f(h2_t a, h2_t b, float c) {
    return c + (float)a.x * (float)b.x + (float)a.y * (float)b.y;
}
#endif

// ---------------------------------------------------------------------------
// Kernel A: xk[row][j] = emb[tokens[row]] @ Wk + b   for both directions.
// ---------------------------------------------------------------------------
__global__ __launch_bounds__(256) void xk_kernel(
    const int* __restrict__ tokens, const float* __restrict__ emb,
    const float* __restrict__ Wk_f, const float* __restrict__ b_f,
    const float* __restrict__ Wk_b, const float* __restrict__ b_b,
    __hip_bfloat16* __restrict__ xk_f, __hip_bfloat16* __restrict__ xk_b)
{
    const int TILE = 16;
    __shared__ float x_lds[TILE][E_];
    const int row0 = blockIdx.x * TILE;
    const int tid  = threadIdx.x;

    for (int idx = tid; idx < TILE * E_; idx += 256) {
        int r = idx / E_, e = idx - r * E_;
        int tok = tokens[row0 + r];
        x_lds[r][e] = emb[(long long)tok * E_ + e];
    }
    __syncthreads();

    float acc[TILE][4];
    #pragma unroll
    for (int r = 0; r < TILE; ++r)
        acc[r][0] = acc[r][1] = acc[r][2] = acc[r][3] = 0.f;

    const float* wf0 = Wk_f + tid;
    const float* wf1 = Wk_f + tid + 256;
    const float* wb0 = Wk_b + tid;
    const float* wb1 = Wk_b + tid + 256;

    for (int e = 0; e < E_; ++e) {
        float w0 = wf0[e * G4];
        float w1 = wf1[e * G4];
        float w2 = wb0[e * G4];
        float w3 = wb1[e * G4];
        #pragma unroll
        for (int r = 0; r < TILE; ++r) {
            float xv = x_lds[r][e];
            acc[r][0] = fmaf(xv, w0, acc[r][0]);
            acc[r][1] = fmaf(xv, w1, acc[r][1]);
            acc[r][2] = fmaf(xv, w2, acc[r][2]);
            acc[r][3] = fmaf(xv, w3, acc[r][3]);
        }
    }

    float bf0 = b_f[tid], bf1 = b_f[tid + 256];
    float bb0 = b_b[tid], bb1 = b_b[tid + 256];
    #pragma unroll
    for (int r = 0; r < TILE; ++r) {
        long long row = row0 + r;
        xk_f[row * G4 + tid]       = __float2bfloat16(acc[r][0] + bf0);
        xk_f[row * G4 + tid + 256] = __float2bfloat16(acc[r][1] + bf1);
        xk_b[row * G4 + tid]       = __float2bfloat16(acc[r][2] + bb0);
        xk_b[row * G4 + tid + 256] = __float2bfloat16(acc[r][3] + bb1);
    }
}

// ---------------------------------------------------------------------------
// Kernel B: LSTM. 256 blocks = (dir, batch), 512 threads = 4 u-parts x 128 q.
// Weights as 64 packed-f16 VGPRs per thread; h broadcast as packed pairs via
// 16 readlanes; 64 v_dot2_f32_f16 per thread per step.
// ---------------------------------------------------------------------------
__device__ __forceinline__ float sigmoid_f(float x) {
    return 1.f / (1.f + __expf(-x));
}
__device__ __forceinline__ float tanh_f(float x) {
    float e = __expf(2.f * x);
    return 1.f - 2.f / (e + 1.f);
}

__global__ __launch_bounds__(512, 2) void lstm_kernel(
    const __hip_bfloat16* __restrict__ xk_f,
    const __hip_bfloat16* __restrict__ xk_b,
    const float* __restrict__ Wr_f, const float* __restrict__ Wr_b,
    __hip_bfloat16* __restrict__ h_buf)
{
    const int bid  = blockIdx.x;
    const int dir  = bid >> 7;
    const int b    = bid & 127;
    const int tid  = threadIdx.x;
    const int part = tid >> 7;       // 0..3 : u-range [part*32, part*32+32)
    const int q    = tid & 127;      // gate-column within each gate

    const float* Wr = dir ? Wr_b : Wr_f;
    const __hip_bfloat16* xk = dir ? xk_b : xk_f;

    // wp[g][i] packs Wr[part*32+2i][g*128+q], Wr[part*32+2i+1][g*128+q]
    h2_t wp[4][16];
    #pragma unroll
    for (int g = 0; g < 4; ++g)
        #pragma unroll
        for (int i = 0; i < 16; ++i)
            wp[g][i] = pk2(
                Wr[(part * 32 + 2 * i)     * G4 + g * 128 + q],
                Wr[(part * 32 + 2 * i + 1) * G4 + g * 128 + q]);

    __shared__ __align__(8) float h_lds[U_];
    __shared__ float part_lds[4][4][U_];   // [gate][part][q]
    if (tid < U_) h_lds[tid] = 0.f;
    float c = 0.f;
    __syncthreads();

    const long long rowbase = (long long)b * T_;
    int t0 = dir ? (T_ - 1) : 0;
    float xk_cur = __bfloat162float(xk[(rowbase + t0) * G4 + tid]);

    for (int s = 0; s < T_; ++s) {
        const int t  = dir ? (T_ - 1 - s) : s;
        const int tn = dir ? (t - 1) : (t + 1);

        // acc init: xk folds into gate g == part exactly once
        float a0 = (part == 0) ? xk_cur : 0.f;
        float a1 = (part == 1) ? xk_cur : 0.f;
        float a2 = (part == 2) ? xk_cur : 0.f;
        float a3 = (part == 3) ? xk_cur : 0.f;

        // prefetch next step's xk (recursion-independent)
        float xk_nxt = 0.f;
        if (s + 1 < T_)
            xk_nxt = __bfloat162float(xk[(rowbase + tn) * G4 + tid]);

        // h pair for this lane: units part*32 + 2*(tid&15), +1 (broadcast read)
        float2 hv = ((const float2*)h_lds)[part * 16 + (tid & 15)];
        int hpi = h2_as_int(pk2(hv.x, hv.y));

        #pragma unroll
        for (int i = 0; i < 16; ++i) {
            h2_t hh = int_as_h2(__builtin_amdgcn_readlane(hpi, i));
            a0 = fdot2_f(hh, wp[0][i], a0);
            a1 = fdot2_f(hh, wp[1][i], a1);
            a2 = fdot2_f(hh, wp[2][i], a2);
            a3 = fdot2_f(hh, wp[3][i], a3);
        }

        part_lds[0][part][q] = a0;
        part_lds[1][part][q] = a1;
        part_lds[2][part][q] = a2;
        part_lds[3][part][q] = a3;
        __syncthreads();

        if (tid < U_) {
            float zi = 0.f, zf = 0.f, zg = 0.f, zo = 0.f;
            #pragma unroll
            for (int p = 0; p < 4; ++p) {
                zi += part_lds[0][p][tid];
                zf += part_lds[1][p][tid];
                zg += part_lds[2][p][tid];
                zo += part_lds[3][p][tid];
            }
            c = sigmoid_f(zf) * c + sigmoid_f(zi) * tanh_f(zg);
            float h = sigmoid_f(zo) * tanh_f(c);
            h_lds[tid] = h;
            h_buf[(rowbase + t) * 256 + dir * U_ + tid] = __float2bfloat16(h);
        }
        __syncthreads();

        xk_cur = xk_nxt;
    }
}

// ---------------------------------------------------------------------------
// Kernel C: em = h_buf(65536x256 bf16) @ ck(256x32) + cb  -> f32 (65536x32).
// ---------------------------------------------------------------------------
__global__ __launch_bounds__(256) void em_kernel(
    const __hip_bfloat16* __restrict__ h_buf,
    const float* __restrict__ ck, const float* __restrict__ cb,
    float* __restrict__ em)
{
    const int tid  = threadIdx.x;
    const int part = tid >> 5;    // 0..7 -> u in [part*32, part*32+32)
    const int k    = tid & 31;

    float ckr[32];
    #pragma unroll
    for (int i = 0; i < 32; ++i)
        ckr[i] = ck[(part * 32 + i) * K_ + k];
    const float cbk = cb[k];

    __shared__ float h_l[8][256];
    __shared__ float part_l[8][8][K_];   // [row][part][k]

    const int r0 = blockIdx.x * 64;

    for (int round = 0; round < 8; ++round) {
        const int rbase = r0 + round * 8;
        #pragma unroll
        for (int j = 0; j < 8; ++j)
            h_l[j][tid] = __bfloat162float(h_buf[(long long)(rbase + j) * 256 + tid]);
        __syncthreads();

        #pragma unroll
        for (int j = 0; j < 8; ++j) {
            float p = 0.f;
            #pragma unroll
            for (int i = 0; i < 32; ++i)
                p = fmaf(h_l[j][part * 32 + i], ckr[i], p);
            part_l[j][part][k] = p;
        }
        __syncthreads();

        {
            int j2 = tid >> 5;
            float e = cbk;
            #pragma unroll
            for (int p = 0; p < 8; ++p) e += part_l[j2][p][k];
            em[(long long)(rbase + j2) * K_ + k] = e;
        }
        __syncthreads();
    }
}

// ---------------------------------------------------------------------------
// Kernel D: CRF logZ. 128 blocks x 1 wave, alpha/exp(trans) in registers.
// ---------------------------------------------------------------------------
#define PF_ 8
__global__ __launch_bounds__(64) void crf_kernel(
    const float* __restrict__ em,
    const float* __restrict__ trans,
    float* __restrict__ out)
{
    const int b    = blockIdx.x;
    const int lane = threadIdx.x;
    const int k    = lane & 31;
    const int half = lane >> 5;

    float etr[16];
    #pragma unroll
    for (int i = 0; i < 16; ++i)
        etr[i] = __expf(trans[(half * 16 + i) * K_ + k]);

    const float* em_b = em + (long long)b * T_ * K_;

    float ep[PF_];
    #pragma unroll
    for (int d = 0; d < PF_; ++d)
        ep[d] = em_b[d * K_ + k];

    float alpha = 0.f;
    for (int tb = 0; tb < T_; tb += PF_) {
        float en[PF_];
        if (tb + PF_ < T_) {
            #pragma unroll
            for (int d = 0; d < PF_; ++d)
                en[d] = em_b[(tb + PF_ + d) * K_ + k];
        } else {
            #pragma unroll
            for (int d = 0; d < PF_; ++d) en[d] = 0.f;
        }

        #pragma unroll
        for (int d = 0; d < PF_; ++d) {
            const int t = tb + d;
            if (t == 0) {
                alpha = ep[d];
            } else {
                float M = __shfl(alpha, 0, 64);
                float p = __expf(alpha - M);
                float acc = 0.f;
                #pragma unroll
                for (int i = 0; i < 16; ++i) {
                    float pv = __shfl(p, half * 16 + i, 64);
                    acc = fmaf(pv, etr[i], acc);
                }
                acc += __shfl_xor(acc, 32, 64);
                alpha = M + __logf(acc) + ep[d];
            }
        }
        #pragma unroll
        for (int d = 0; d < PF_; ++d) ep[d] = en[d];
    }

    float m = alpha;
    #pragma unroll
    for (int d = 1; d < 32; d <<= 1)
        m = fmaxf(m, __shfl_xor(m, d, 64));
    float s = __expf(alpha - m);
    #pragma unroll
    for (int d = 1; d < 32; d <<= 1)
        s += __shfl_xor(s, d, 64);
    if (lane == 0) out[b] = m + __logf(s);
}

// ---------------------------------------------------------------------------
extern "C" void kernel_launch(void* const* d_in, const int* in_sizes, int n_in,
                              void* d_out, int out_size, void* d_ws, size_t ws_size,
                              hipStream_t stream)
{
    const int*   tokens = (const int*)  d_in[0];
    const float* emb    = (const float*)d_in[1];
    const float* Wk_f   = (const float*)d_in[2];
    const float* Wr_f   = (const float*)d_in[3];
    const float* b_f    = (const float*)d_in[4];
    const float* Wk_b   = (const float*)d_in[5];
    const float* Wr_b   = (const float*)d_in[6];
    const float* b_b    = (const float*)d_in[7];
    const float* ck     = (const float*)d_in[8];
    const float* cb     = (const float*)d_in[9];
    const float* trans  = (const float*)d_in[10];
    float* out = (float*)d_out;

    const long long ROWS = (long long)B_ * T_;     // 65536
    __hip_bfloat16* xk_f  = (__hip_bfloat16*)d_ws;
    __hip_bfloat16* xk_b  = xk_f + ROWS * G4;
    __hip_bfloat16* h_buf = xk_b + ROWS * G4;
    float* em = (float*)d_ws;                      // alias, safe by ordering

    hipLaunchKernelGGL(xk_kernel, dim3((int)(ROWS / 16)), dim3(256), 0, stream,
                       tokens, emb, Wk_f, b_f, Wk_b, b_b, xk_f, xk_b);
    hipLaunchKernelGGL(lstm_kernel, dim3(256), dim3(512), 0, stream,
                       xk_f, xk_b, Wr_f, Wr_b, h_buf);
    hipLaunchKernelGGL(em_kernel, dim3((int)(ROWS / 64)), dim3(256), 0, stream,
                       h_buf, ck, cb, em);
    hipLaunchKernelGGL(crf_kernel, dim3(B_), dim3(64), 0, stream,
                       em, trans, out);
}